// Round 13
// baseline (25.490 us; speedup 1.0000x reference)
//
#include <hip/hip_runtime.h>
#include <hip/hip_fp16.h>

// Problem constants (from reference setup_inputs)
constexpr int Bn = 256;
constexpr int Nn = 16384;
constexpr int Hh = 96;
constexpr int Ww = 96;

constexpr int THREADS = 1024;
constexpr int CHUNKS  = 2;                 // 512 blocks -> 2 per CU -> 32 waves/CU

// Dup-pair fp16 LDS entries (4B): entry c = (pad[c], pad[c+1]).
//   Edge: pad rows 0..99 (2-zero pad each side), 100x100 = 10000 entries
//   Mask: pad rows 1..98 stored as s-rows 0..97,   98x100 =  9800 entries
// Total 19800 x 4B = 79.2 KB -> 2 blocks/CU.
// Per corner: edge 4x4 = 4 ds_read2_b32, mask 2x2 = 1 ds_read2_b32.
constexpr int MOFF = 10000;
constexpr int TOTENT = 19800;

static __device__ inline float2 up2(__half2 h) { return __half22float2(h); }
static __device__ inline __half2 H2(unsigned u) { return *(__half2*)&u; }
static __device__ inline unsigned U32(__half2 h) { return *(unsigned*)&h; }

// ROCm 7.2 headers lack __hmax2; emit v_pk_max_f16 directly (proven in R9).
static __device__ inline __half2 pkmax2(__half2 a, __half2 b)
{
    unsigned ai = U32(a), bi = U32(b), ri;
    asm("v_pk_max_f16 %0, %1, %2" : "=v"(ri) : "v"(ai), "v"(bi));
    return H2(ri);
}

// ---- per-corner macros (named scalars only; no arrays -> no scratch) ----
#define ADDR(sfx, CX, CY)                                                   \
    float ix##sfx = fmaf(CX, 96.f, -0.5f);                                  \
    float iy##sfx = fmaf(CY, 96.f, -0.5f);                                  \
    float fx##sfx = floorf(ix##sfx), fy##sfx = floorf(iy##sfx);             \
    float wx##sfx = ix##sfx - fx##sfx, wy##sfx = iy##sfx - fy##sfx;         \
    int v##sfx  = (int)fy##sfx * 100 + (int)fx##sfx;                        \
    int cb##sfx = v##sfx + 101;                                             \
    int c3##sfx = v##sfx + 401;                                             \
    int mb##sfx = v##sfx + MOFF + 102;

#define ISSUE(sfx)                                                          \
    __half2 a0##sfx = sB[cb##sfx],       d0##sfx = sB[cb##sfx + 2];         \
    __half2 a1##sfx = sB[cb##sfx + 100], d1##sfx = sB[cb##sfx + 102];       \
    __half2 a2##sfx = sB[cb##sfx + 200], d2##sfx = sB[cb##sfx + 202];       \
    __half2 a3##sfx = sB[c3##sfx],       d3##sfx = sB[c3##sfx + 2];         \
    __half2 ma##sfx = sB[mb##sfx],       mc##sfx = sB[mb##sfx + 100];

// Packed-fp16 edge: dup-pair entries a=(p0,p1), d=(p2,p3).
//   mid = alignbit(d,a) = (p1,p2);  sft = alignbit(d,d) = (p3,p2)
//   hA = pkfma(wx2, mid-a, a) = (h0,h1);  hB = pkfma(wx2, sft-d, d) = (h2,junk)
#define EROW(sfx, R)                                                        \
    __half2 hA##R##sfx, hB##R##sfx;                                         \
    {                                                                       \
        unsigned ua = U32(a##R##sfx), ud = U32(d##R##sfx);                  \
        __half2 mid = H2((ua >> 16) | (ud << 16));                          \
        __half2 sft = H2((ud >> 16) | (ud << 16));                          \
        hA##R##sfx = __hfma2(wx2##sfx, __hsub2(mid, a##R##sfx), a##R##sfx); \
        hB##R##sfx = __hfma2(wx2##sfx, __hsub2(sft, d##R##sfx), d##R##sfx); \
    }

#define COMPUTE(sfx)                                                        \
    {                                                                       \
        __half2 wx2##sfx = __half2half2(__float2half_rn(wx##sfx));          \
        __half2 wy2##sfx = __half2half2(__float2half_rn(wy##sfx));          \
        EROW(sfx, 0) EROW(sfx, 1) EROW(sfx, 2) EROW(sfx, 3)                 \
        __half2 vA0 = __hfma2(wy2##sfx, __hsub2(hA1##sfx, hA0##sfx), hA0##sfx); \
        __half2 vA1 = __hfma2(wy2##sfx, __hsub2(hA2##sfx, hA1##sfx), hA1##sfx); \
        __half2 vA2 = __hfma2(wy2##sfx, __hsub2(hA3##sfx, hA2##sfx), hA2##sfx); \
        __half2 vB0 = __hfma2(wy2##sfx, __hsub2(hB1##sfx, hB0##sfx), hB0##sfx); \
        __half2 vB1 = __hfma2(wy2##sfx, __hsub2(hB2##sfx, hB1##sfx), hB1##sfx); \
        __half2 vB2 = __hfma2(wy2##sfx, __hsub2(hB3##sfx, hB2##sfx), hB2##sfx); \
        __half2 mAh = pkmax2(pkmax2(vA0, vA1), vA2);   /* (maxc0, maxc1) */ \
        __half2 mBh = pkmax2(pkmax2(vB0, vB1), vB2);   /* (maxc2, junk) */  \
        unsigned uA = U32(mAh);                                             \
        __half2 mm = pkmax2(mAh, H2((uA >> 16) | (uA << 16)));              \
        __half2 mm2 = pkmax2(mm, mBh);                 /* lo = max of 9 */  \
        eAcc += __half2float(__low2half(mm2));                              \
        float2 qa = up2(ma##sfx), qc = up2(mc##sfx);                        \
        float wx = wx##sfx, wy = wy##sfx;                                   \
        float t = fmaf(wx, qa.y - qa.x, qa.x);                              \
        float u = fmaf(wx, qc.y - qc.x, qc.x);                              \
        float m = fmaf(wy, u - t, t);                                       \
        float d = m - 0.5f;                                                 \
        mAcc = fmaf(d, d, mAcc);                                            \
    }

__global__ __launch_bounds__(THREADS, 8)
void geo_kernel(const float* __restrict__ corners,
                const float* __restrict__ edge,
                const float* __restrict__ mask,
                float2* __restrict__ partial)
{
    __shared__ __half2 sB[TOTENT];
    __shared__ float redE[THREADS / 64];
    __shared__ float redM[THREADS / 64];

    const int b     = blockIdx.x >> 1;     // CHUNKS == 2
    const int chunk = blockIdx.x & 1;
    const int tid   = threadIdx.x;

    // --- zero border entries (disjoint from interior fill) ---
    {
        const __half2 z2 = __halves2half2(__ushort_as_half(0), __ushort_as_half(0));
        for (int i = tid; i < 1176; i += THREADS) {
            int idx;
            if (i < 200)        idx = i;                          // edge pad rows 0,1
            else if (i < 400)   idx = 9600 + i;                   // edge pad rows 98,99
            else if (i < 500)   idx = MOFF + (i - 400);           // mask s-row 0
            else if (i < 600)   idx = MOFF + 9200 + i;            // mask s-row 97
            else if (i < 888) { int k = i - 600; int r = k / 3; int c3 = k - 3 * r;
                                int c = (c3 == 0) ? 0 : (97 + c3);
                                idx = (r + 2) * 100 + c; }        // edge rows 2..97
            else              { int k = i - 888; int r = k / 3; int c3 = k - 3 * r;
                                int c = (c3 == 0) ? 0 : (97 + c3);
                                idx = MOFF + (r + 1) * 100 + c; } // mask s-rows 1..96
            sB[idx] = z2;
        }
    }

    // --- fill interiors with dup-pair fp16 (disjoint from borders) ---
    {
        const float* ebase = edge + (size_t)b * Hh * Ww;
        const float* mbase = mask + (size_t)b * Hh * Ww;
        for (int i = tid; i < 96 * 48; i += THREADS) {
            int r = i / 48;
            int j = i - 48 * r;
            const float* erow = ebase + r * Ww;
            const float* mrow = mbase + r * Ww;
            float2 ae = *(const float2*)(erow + 2 * j);
            float2 am = *(const float2*)(mrow + 2 * j);
            float ne = (2 * j + 2 < Ww) ? erow[2 * j + 2] : 0.f;
            float nm = (2 * j + 2 < Ww) ? mrow[2 * j + 2] : 0.f;
            int eb2 = (r + 2) * 100 + 2 * j + 2;
            sB[eb2]     = __float22half2_rn(make_float2(ae.x, ae.y));
            sB[eb2 + 1] = __float22half2_rn(make_float2(ae.y, ne));
            int mb2 = MOFF + (r + 1) * 100 + 2 * j + 2;
            sB[mb2]     = __float22half2_rn(make_float2(am.x, am.y));
            sB[mb2 + 1] = __float22half2_rn(make_float2(am.y, nm));
            if (j == 0) {
                sB[(r + 2) * 100 + 1]        = __float22half2_rn(make_float2(0.f, ae.x));
                sB[MOFF + (r + 1) * 100 + 1] = __float22half2_rn(make_float2(0.f, am.x));
            }
        }
    }
    __syncthreads();

    // --- corner loop: 4 float4 (8 corners), pairwise software-pipelined ---
    const float4* c4 =
        (const float4*)(corners + (size_t)b * Nn * 2 + (size_t)chunk * (Nn / CHUNKS) * 2);
    float eAcc = 0.f, mAcc = 0.f;

    float4 nxt = c4[tid];
#pragma unroll
    for (int k = 0; k < 4; ++k) {
        float4 cur = nxt;
        if (k < 3) nxt = c4[(k + 1) * THREADS + tid];   // prefetch next pair

        ADDR(A, cur.x, cur.y)
        ISSUE(A)                      // 5 ds_read2 for corner A in flight
        ADDR(B, cur.z, cur.w)
        ISSUE(B)                      // 5 more for corner B in flight
        COMPUTE(A)                    // waits only on A's reads
        COMPUTE(B)
    }

    // --- reduce: wave shuffle, cross-wave via LDS, per-block partial ---
#pragma unroll
    for (int off = 32; off > 0; off >>= 1) {
        eAcc += __shfl_xor(eAcc, off);
        mAcc += __shfl_xor(mAcc, off);
    }
    const int wv = tid >> 6;
    const int ln = tid & 63;
    if (ln == 0) { redE[wv] = eAcc; redM[wv] = mAcc; }
    __syncthreads();

    if (tid == 0) {
        float e = 0.f, m = 0.f;
#pragma unroll
        for (int w = 0; w < THREADS / 64; ++w) { e += redE[w]; m += redM[w]; }
        partial[blockIdx.x] = make_float2(e, m);
    }
}

// Final reduction over the 512 block partials; no atomics anywhere.
__global__ __launch_bounds__(512)
void geo_reduce(const float2* __restrict__ partial, float* __restrict__ out)
{
    __shared__ double rE[8];
    __shared__ double rM[8];
    const int tid = threadIdx.x;
    float2 p = partial[tid];
    double e = (double)p.x, m = (double)p.y;
#pragma unroll
    for (int off = 32; off > 0; off >>= 1) {
        e += __shfl_xor(e, off);
        m += __shfl_xor(m, off);
    }
    if ((tid & 63) == 0) { rE[tid >> 6] = e; rM[tid >> 6] = m; }
    __syncthreads();
    if (tid == 0) {
        double se = 0.0, sm = 0.0;
#pragma unroll
        for (int w = 0; w < 8; ++w) { se += rE[w]; sm += rM[w]; }
        const double inv = 1.0 / (double)((long long)Bn * (long long)Nn);
        double edge_loss = 1.0 - se * inv;
        double mask_loss = sm * inv;
        out[0] = (float)(edge_loss + 2.0 * mask_loss);
    }
}

extern "C" void kernel_launch(void* const* d_in, const int* in_sizes, int n_in,
                              void* d_out, int out_size, void* d_ws, size_t ws_size,
                              hipStream_t stream)
{
    const float* corners = (const float*)d_in[0];
    const float* edge    = (const float*)d_in[1];
    const float* mask    = (const float*)d_in[2];
    float* out      = (float*)d_out;
    float2* partial = (float2*)d_ws;

    geo_kernel<<<Bn * CHUNKS, THREADS, 0, stream>>>(corners, edge, mask, partial);
    geo_reduce<<<1, 512, 0, stream>>>(partial, out);
}